// Round 13
// baseline (370.629 us; speedup 1.0000x reference)
//
#include <hip/hip_runtime.h>
#include <stdint.h>

#define NTOK 4096
#define HD 64
#define DIMC 1024

typedef __attribute__((ext_vector_type(8))) short s16x8;
typedef __attribute__((ext_vector_type(4))) float f32x4;

#if __has_builtin(__builtin_amdgcn_exp2f)
#define EXP2(x) __builtin_amdgcn_exp2f(x)
#else
#define EXP2(x) exp2f(x)
#endif

__device__ inline unsigned short f2bf(float f) {
  union { float f; unsigned u; } v; v.f = f;
  unsigned r = v.u + 0x7FFFu + ((v.u >> 16) & 1u);
  return (unsigned short)(r >> 16);
}

__device__ inline unsigned cvt_pk_bf16(float lo, float hi) {
  unsigned r;
  asm("v_cvt_pk_bf16_f32 %0, %1, %2" : "=v"(r) : "v"(lo), "v"(hi));
  return r;
}

__device__ inline float bf2f(unsigned short u) {
  union { unsigned u; float f; } v; v.u = ((unsigned)u) << 16;
  return v.f;
}

__device__ inline void gld16(const void* g, void* s) {
  __builtin_amdgcn_global_load_lds((const __attribute__((address_space(1))) void*)g,
                                   (__attribute__((address_space(3))) void*)s, 16, 0, 0);
}

// ---------------- fp32 -> bf16 convert (x and w_qkv only) --------------------
#define N4_X   1048576
#define N4_WQ  786432
__global__ void cvt_all(const float4* __restrict__ x, const float4* __restrict__ wq,
                        ushort4* __restrict__ xb, ushort4* __restrict__ wqb) {
  int i = blockIdx.x * 256 + threadIdx.x;
  const float4* s; ushort4* d; int off;
  if (i < N4_X) { s = x; d = xb; off = i; }
  else { s = wq; d = wqb; off = i - N4_X; }
  float4 v = s[off];
  ushort4 o;
  o.x = f2bf(v.x); o.y = f2bf(v.y); o.z = f2bf(v.z); o.w = f2bf(v.w);
  d[off] = o;
}

// ---------------- GEMM1: QKV projection (both inputs K-major bf16) -----------
#define QSCALE 0.18033688011112042f  /* 0.125 * log2(e) */
__global__ __launch_bounds__(256) void gemm_qkv(
    const unsigned short* __restrict__ A,
    const unsigned short* __restrict__ B,
    unsigned short* __restrict__ qb,
    unsigned short* __restrict__ kb,
    unsigned short* __restrict__ vtb)
{
  __shared__ unsigned short As[128 * 32];
  __shared__ unsigned short Bs[128 * 32];
  const int t = threadIdx.x;
  const int l = t & 63;
  const int w = t >> 6;
  const int wr = w >> 1, wc = w & 1;
  const int bm = blockIdx.x, bn = blockIdx.y;
  const int K = 1024;

  f32x4 acc[4][4];
#pragma unroll
  for (int m = 0; m < 4; ++m)
#pragma unroll
    for (int n = 0; n < 4; ++n)
#pragma unroll
      for (int r = 0; r < 4; ++r) acc[m][n][r] = 0.f;

  for (int kt = 0; kt < K; kt += 32) {
    __syncthreads();
#pragma unroll
    for (int j = 0; j < 2; ++j) {
      const int o = j * 4096 + t * 16;
      const int row = o >> 6;
      const int cole = (o & 63) >> 1;
      gld16(A + (size_t)(bm * 128 + row) * K + kt + cole, (char*)As + o);
      gld16(B + (size_t)(bn * 128 + row) * K + kt + cole, (char*)Bs + o);
    }
    __syncthreads();
    s16x8 af[4], bfr[4];
    const int cb = (l >> 4) * 16;
#pragma unroll
    for (int m = 0; m < 4; ++m)
      af[m] = *(const s16x8*)((const char*)As + (wr * 64 + m * 16 + (l & 15)) * 64 + cb);
#pragma unroll
    for (int n = 0; n < 4; ++n)
      bfr[n] = *(const s16x8*)((const char*)Bs + (wc * 64 + n * 16 + (l & 15)) * 64 + cb);
#pragma unroll
    for (int m = 0; m < 4; ++m)
#pragma unroll
      for (int n = 0; n < 4; ++n)
        acc[m][n] = __builtin_amdgcn_mfma_f32_16x16x32_bf16(af[m], bfr[n], acc[m][n], 0, 0, 0);
  }

#pragma unroll
  for (int m = 0; m < 4; ++m) {
#pragma unroll
    for (int n = 0; n < 4; ++n) {
#pragma unroll
      for (int r = 0; r < 4; ++r) {
        const int gm = bm * 128 + wr * 64 + m * 16 + (l >> 4) * 4 + r;
        const int gn = bn * 128 + wc * 64 + n * 16 + (l & 15);
        const float val = acc[m][n][r];
        const int part = gn >> 10;
        const int h = (gn >> 6) & 15;
        const int dd = gn & 63;
        if (part == 0)      qb[((size_t)h * NTOK + gm) * HD + dd] = f2bf(val * QSCALE);
        else if (part == 1) kb[((size_t)h * NTOK + gm) * HD + dd] = f2bf(val);
        else                vtb[((size_t)h * HD + dd) * NTOK + gm] = f2bf(val);
      }
    }
  }
}

// ---------------- Flash attention, split-K x2 + fused last-block combine -----
// r12-proven body (counted-vmcnt loop). After partial write, the 2 blocks of a
// (h,qt) pair rendezvous via device-scope atomic; the 2nd-finisher combines
// both partials (own is L2-hot) and writes normalized bf16 into aob.
__global__ __launch_bounds__(128, 4) void fa_split(
    const unsigned short* __restrict__ Q,
    const unsigned short* __restrict__ Kin,
    const unsigned short* __restrict__ Vt,
    unsigned short* __restrict__ Opart,   // [2][16][4096][64] bf16 unnormalized
    float* __restrict__ Lpart,            // [2][16][4096] f32
    int* __restrict__ flags,              // [16*64] zeroed per launch
    unsigned short* __restrict__ aob)     // [4096][1024] bf16
{
  __shared__ unsigned short Ks[2][32 * 64];
  __shared__ unsigned short Vs[2][64 * 32];
  __shared__ int sOld;

  const int t = threadIdx.x, l = t & 63, w = t >> 6;  // w in {0,1}
  const int g = l >> 4, q = l & 15;
  const int wg = blockIdx.x;
  const int h = wg & 15;                    // h&7 -> XCD affinity
  const int qt = (wg >> 4) & 63;
  const int half = wg >> 10;
  const int q0 = qt * 64 + w * 32;
  const int kbase0 = half * (NTOK / 2);
  const unsigned short* Qh = Q + (size_t)h * NTOK * HD;
  const unsigned short* Kh = Kin + (size_t)h * NTOK * HD;
  const unsigned short* Vh = Vt + (size_t)h * HD * NTOK;

  int offK[2], offV[2];
#pragma unroll
  for (int j = 0; j < 2; ++j) {
    const int o = j * 2048 + t * 16;        // 0..4095
    const int rho = o >> 7;                 // K LDS row 0..31
    const int c = o & 127;
    const int n = ((rho & 12) << 1) | ((rho & 16) >> 2) | (rho & 3);
    offK[j] = n * 128 + (c ^ ((rho & 7) << 4));
    const int rv = o >> 6;                  // V LDS row (=d) 0..63
    const int cv = o & 63;
    offV[j] = rv * (NTOK * 2) + (cv ^ (((rv >> 1) & 3) << 4));
  }

  s16x8 qf[2][2];
#pragma unroll
  for (int rb = 0; rb < 2; ++rb)
#pragma unroll
    for (int tq = 0; tq < 2; ++tq)
      qf[rb][tq] = *(const s16x8*)(Qh + (size_t)(q0 + rb * 16 + q) * HD + tq * 32 + g * 8);

  s16x8 ones;
#pragma unroll
  for (int i = 0; i < 8; ++i) ones[i] = (short)0x3F80;

  f32x4 oacc[2][4], lacc[2];
#pragma unroll
  for (int rb = 0; rb < 2; ++rb) {
#pragma unroll
    for (int db = 0; db < 4; ++db)
#pragma unroll
      for (int r = 0; r < 4; ++r) oacc[rb][db][r] = 0.f;
#pragma unroll
    for (int r = 0; r < 4; ++r) lacc[rb][r] = 0.f;
  }

  // prologue: stage tile 0 + full drain (also retires Q-fragment loads)
#pragma unroll
  for (int j = 0; j < 2; ++j) {
    const int o = j * 2048 + t * 16;
    gld16((const char*)Kh + (size_t)kbase0 * 128 + offK[j], (char*)Ks[0] + o);
    gld16((const char*)Vh + (size_t)kbase0 * 2 + offV[j], (char*)Vs[0] + o);
  }
  __syncthreads();

  int cur = 0;
  const int NIT = (NTOK / 2) / 32;
  for (int it = 0; it < NIT; ++it) {
    if (it + 1 < NIT) {
      const char* kp = (const char*)Kh + (size_t)(kbase0 + (it + 1) * 32) * 128;
      const char* vp = (const char*)Vh + (size_t)(kbase0 + (it + 1) * 32) * 2;
#pragma unroll
      for (int j = 0; j < 2; ++j) {
        const int o = j * 2048 + t * 16;
        gld16(kp + offK[j], (char*)Ks[cur ^ 1] + o);
        gld16(vp + offV[j], (char*)Vs[cur ^ 1] + o);
      }
      asm volatile("s_waitcnt vmcnt(4)" ::: "memory");
    } else {
      asm volatile("s_waitcnt vmcnt(0)" ::: "memory");
    }
    __builtin_amdgcn_sched_barrier(0);
    __builtin_amdgcn_s_barrier();     // buf[cur] DMA visible to both waves
    __builtin_amdgcn_sched_barrier(0);

    const char* kb = (const char*)Ks[cur];
    const char* vb = (const char*)Vs[cur];

    f32x4 sc[2][2];
    __builtin_amdgcn_s_setprio(1);
#pragma unroll
    for (int kb2 = 0; kb2 < 2; ++kb2) {
      const int row = kb2 * 16 + q;
      const int swz = (row & 7) << 4;
      s16x8 kf0 = *(const s16x8*)(kb + row * 128 + ((g * 16) ^ swz));
      s16x8 kf1 = *(const s16x8*)(kb + row * 128 + ((64 + g * 16) ^ swz));
#pragma unroll
      for (int rb = 0; rb < 2; ++rb) {
        f32x4 z = {0.f, 0.f, 0.f, 0.f};
        z = __builtin_amdgcn_mfma_f32_16x16x32_bf16(kf0, qf[rb][0], z, 0, 0, 0);
        sc[rb][kb2] = __builtin_amdgcn_mfma_f32_16x16x32_bf16(kf1, qf[rb][1], z, 0, 0, 0);
      }
    }
    __builtin_amdgcn_s_setprio(0);

    union PU { unsigned u[4]; s16x8 v; } pu[2];
#pragma unroll
    for (int rb = 0; rb < 2; ++rb) {
      pu[rb].u[0] = cvt_pk_bf16(EXP2(sc[rb][0][0]), EXP2(sc[rb][0][1]));
      pu[rb].u[1] = cvt_pk_bf16(EXP2(sc[rb][0][2]), EXP2(sc[rb][0][3]));
      pu[rb].u[2] = cvt_pk_bf16(EXP2(sc[rb][1][0]), EXP2(sc[rb][1][1]));
      pu[rb].u[3] = cvt_pk_bf16(EXP2(sc[rb][1][2]), EXP2(sc[rb][1][3]));
    }

    __builtin_amdgcn_s_setprio(1);
    const int vswz = ((q >> 1) & 3) << 4;
#pragma unroll
    for (int db = 0; db < 4; ++db) {
      const int row = db * 16 + q;
      s16x8 vf = *(const s16x8*)(vb + row * 64 + ((g * 16) ^ vswz));
#pragma unroll
      for (int rb = 0; rb < 2; ++rb)
        oacc[rb][db] = __builtin_amdgcn_mfma_f32_16x16x32_bf16(vf, pu[rb].v, oacc[rb][db], 0, 0, 0);
    }
#pragma unroll
    for (int rb = 0; rb < 2; ++rb)
      lacc[rb] = __builtin_amdgcn_mfma_f32_16x16x32_bf16(ones, pu[rb].v, lacc[rb], 0, 0, 0);
    __builtin_amdgcn_s_setprio(0);

    __builtin_amdgcn_sched_barrier(0);
    __builtin_amdgcn_s_barrier();     // reads consumed before next DMA overwrite
    __builtin_amdgcn_sched_barrier(0);
    cur ^= 1;
  }

  // epilogue: write unnormalized bf16 O^T partials + lsum
  const size_t pbase = ((size_t)(half * 16 + h) * NTOK);
#pragma unroll
  for (int rb = 0; rb < 2; ++rb) {
    const int nn = q0 + rb * 16 + q;
#pragma unroll
    for (int db = 0; db < 4; ++db) {
      uint2 pr;
      pr.x = cvt_pk_bf16(oacc[rb][db][0], oacc[rb][db][1]);
      pr.y = cvt_pk_bf16(oacc[rb][db][2], oacc[rb][db][3]);
      *(uint2*)(Opart + (pbase + nn) * HD + db * 16 + g * 4) = pr;
    }
    if (g == 0) Lpart[pbase + nn] = lacc[rb][0];
  }

  // ---- fused combine: 2nd block of the (h,qt) pair finishes -----------------
  __threadfence();                 // release: our partial + lsum visible
  __syncthreads();                 // all threads' writes + fences done
  if (t == 0) sOld = atomicAdd(&flags[(h << 6) | qt], 1);
  __syncthreads();
  if (sOld == 1) {
    __threadfence();               // acquire: see peer block's partial
    const int q0b = qt * 64;
    const size_t s1 = (size_t)16 * NTOK * HD;
    const int nl = t >> 1;                   // row 0..63
    const int nn = q0b + nl;
    const float inv = 1.f / (Lpart[(size_t)h * NTOK + nn] +
                             Lpart[(size_t)16 * NTOK + (size_t)h * NTOK + nn]);
    const size_t ebase = ((size_t)h * NTOK + nn) * HD;
#pragma unroll
    for (int k2 = 0; k2 < 8; ++k2) {
      const int c4 = (t & 1) * 8 + k2;       // 0..15
      ushort4 p0 = *(const ushort4*)(Opart + ebase + c4 * 4);
      ushort4 p1 = *(const ushort4*)(Opart + ebase + s1 + c4 * 4);
      ushort4 o;
      o.x = f2bf((bf2f(p0.x) + bf2f(p1.x)) * inv);
      o.y = f2bf((bf2f(p0.y) + bf2f(p1.y)) * inv);
      o.z = f2bf((bf2f(p0.z) + bf2f(p1.z)) * inv);
      o.w = f2bf((bf2f(p0.w) + bf2f(p1.w)) * inv);
      *(ushort4*)(aob + (size_t)nn * DIMC + h * HD + c4 * 4) = o;
    }
  }
}

// ---------------- GEMM2: out = ao * wout^T; A bf16 gld16, B fp32 reg-cvt -----
__global__ __launch_bounds__(256) void gemm_out(
    const unsigned short* __restrict__ A,      // aob bf16 [4096][1024]
    const float* __restrict__ wout,            // [1024][1024] fp32 row-major
    float* __restrict__ outf)                  // [4096][1024] fp32
{
  __shared__ unsigned short As[128 * 32];
  __shared__ unsigned short Bs[128 * 32];
  const int t = threadIdx.x;
  const int l = t & 63;
  const int w = t >> 6;
  const int wr = w >> 1, wc = w & 1;
  const int bm = blockIdx.x, bn = blockIdx.y;

  f32x4 acc[4][4];
#pragma unroll
  for (int m = 0; m < 4; ++m)
#pragma unroll
    for (int n = 0; n < 4; ++n)
#pragma unroll
      for (int r = 0; r < 4; ++r) acc[m][n][r] = 0.f;

  for (int kt = 0; kt < 1024; kt += 32) {
    __syncthreads();
#pragma unroll
    for (int j = 0; j < 2; ++j) {
      const int o = j * 4096 + t * 16;
      const int row = o >> 6;
      const int cole = (o & 63) >> 1;
      gld16(A + (size_t)(bm * 128 + row) * 1024 + kt + cole, (char*)As + o);
      const float* bsrc = wout + (size_t)(bn * 128 + row) * 1024 + kt + cole;
      float4 b0 = *(const float4*)bsrc;
      float4 b1 = *(const float4*)(bsrc + 4);
      union PB { unsigned u[4]; s16x8 v; } pb;
      pb.u[0] = cvt_pk_bf16(b0.x, b0.y);
      pb.u[1] = cvt_pk_bf16(b0.z, b0.w);
      pb.u[2] = cvt_pk_bf16(b1.x, b1.y);
      pb.u[3] = cvt_pk_bf16(b1.z, b1.w);
      *(s16x8*)((char*)Bs + o) = pb.v;
    }
    __syncthreads();
    s16x8 af[4], bfr[4];
    const int cb = (l >> 4) * 16;
#pragma unroll
    for (int m = 0; m < 4; ++m)
      af[m] = *(const s16x8*)((const char*)As + (wr * 64 + m * 16 + (l & 15)) * 64 + cb);
#pragma unroll
    for (int n = 0; n < 4; ++n)
      bfr[n] = *(const s16x8*)((const char*)Bs + (wc * 64 + n * 16 + (l & 15)) * 64 + cb);
#pragma unroll
    for (int m = 0; m < 4; ++m)
#pragma unroll
      for (int n = 0; n < 4; ++n)
        acc[m][n] = __builtin_amdgcn_mfma_f32_16x16x32_bf16(af[m], bfr[n], acc[m][n], 0, 0, 0);
  }

#pragma unroll
  for (int m = 0; m < 4; ++m)
#pragma unroll
    for (int n = 0; n < 4; ++n)
#pragma unroll
      for (int r = 0; r < 4; ++r) {
        const int gm = bm * 128 + wr * 64 + m * 16 + (l >> 4) * 4 + r;
        const int gn = bn * 128 + wc * 64 + n * 16 + (l & 15);
        outf[(size_t)gm * 1024 + gn] = acc[m][n][r];
      }
}

extern "C" void kernel_launch(void* const* d_in, const int* in_sizes, int n_in,
                              void* d_out, int out_size, void* d_ws, size_t ws_size,
                              hipStream_t stream) {
  const float* x    = (const float*)d_in[0];
  const float* wqkv = (const float*)d_in[1];
  const float* wout = (const float*)d_in[2];
  // d_in[3] (hilbert indices): softmax attention is permutation-equivariant -> no-op
  float* out = (float*)d_out;
  char* ws = (char*)d_ws;

  // layout (41 MiB peak): Opart[0,16M) overlays xb[0,8M)+wqkvb[8M,14M)
  //   Lp[16M,16.5M) | flags[16.5M,+4K) | Qb[17M,25M) | Kb[25M,33M) | Vtb[33M,41M)
  //   aob overlays Qb (dead after fa_split... written by fa_split finishers;
  //   NOTE: Qb is still being READ by fa_split while aob is written -> use a
  //   separate region instead: aob at [41M,49M).
  unsigned short* Opart = (unsigned short*)(ws);
  unsigned short* xb    = (unsigned short*)(ws);
  unsigned short* wqkvb = (unsigned short*)(ws + 8388608);
  float*          Lp    = (float*)(ws + 16777216);
  int*            flags = (int*)(ws + 17301504);
  unsigned short* Qb    = (unsigned short*)(ws + 17825792);
  unsigned short* Kb    = (unsigned short*)(ws + 26214400);
  unsigned short* Vtb   = (unsigned short*)(ws + 34603008);
  unsigned short* aob   = (unsigned short*)(ws + 42991616);   // 8 MiB, ends 49 MiB

  hipMemsetAsync(flags, 0, 4096, stream);

  cvt_all<<<7168, 256, 0, stream>>>((const float4*)x, (const float4*)wqkv,
                                    (ushort4*)xb, (ushort4*)wqkvb);

  // QKV projection: M=4096, N=3072, K=1024
  gemm_qkv<<<dim3(32, 24), 256, 0, stream>>>(xb, wqkvb, Qb, Kb, Vtb);

  // flash attention split-K x2 with fused last-block combine
  fa_split<<<2048, 128, 0, stream>>>(Qb, Kb, Vtb, Opart, Lp, flags, aob);

  // output projection: M=4096, N=1024, K=1024 -> fp32 d_out
  gemm_out<<<dim3(32, 8), 256, 0, stream>>>(aob, wout, out);
}